// Round 7
// baseline (626.779 us; speedup 1.0000x reference)
//
#include <hip/hip_runtime.h>
#include <math.h>

typedef unsigned short u16;
typedef unsigned int   u32;
typedef __attribute__((ext_vector_type(8))) short bf16x8;
typedef __attribute__((ext_vector_type(4))) float f32x4;
typedef __attribute__((ext_vector_type(4))) u32   u32x4;

__device__ __forceinline__ float b2f(u16 u) {
  union { u32 i; float f; } v; v.i = ((u32)u) << 16; return v.f;
}
__device__ __forceinline__ u16 f2b(float f) {
  union { u32 i; float f; } v; v.f = f;
  u32 r = v.i + 0x7FFFu + ((v.i >> 16) & 1u);
  return (u16)(r >> 16);
}
__device__ __forceinline__ float blo(u32 w) {
  union { u32 i; float f; } v; v.i = w << 16; return v.f;
}
__device__ __forceinline__ float bhi(u32 w) {
  union { u32 i; float f; } v; v.i = w & 0xFFFF0000u; return v.f;
}
// async global->LDS, 16B per lane; dest is wave-uniform base + lane*16
__device__ __forceinline__ void ld_lds16(const u16* g, u16* l) {
  __builtin_amdgcn_global_load_lds((const __attribute__((address_space(1))) void*)g,
                                   (__attribute__((address_space(3))) void*)l, 16, 0, 0);
}

// local dtype detection (wave-uniform, ~1 load + 2 ballots; no cross-kernel flag dep)
__device__ __forceinline__ int is_bf16_w(const void* x) {
  int lane = threadIdx.x & 63;
  u32 w = ((const u32*)x)[lane];
  u16 a = (u16)(w & 0xFFFF), b = (u16)(w >> 16);
  int ea = (a >> 7) & 0xFF, eb = (b >> 7) & 0xFF;
  bool oka = (a == 0) || (ea >= 90 && ea <= 134);
  bool okb = (b == 0) || (eb >= 90 && eb <= 134);
  int cnt = (int)__popcll(__ballot(oka)) + (int)__popcll(__ballot(okb));
  return cnt >= 110;
}
__device__ __forceinline__ int is_i64_w(const int* ei) {
  int lane = threadIdx.x & 63;
  int v = (lane < 16) ? (ei[2 * lane + 1] == 0) : 0;
  return (int)__popcll(__ballot(v)) >= 15;
}

#define NN 50000
#define NE 400000
#define NT 450000   // NE + NN self loops

// ---------------- fused prep: convert_x (f32 path) + w1t + w23t + params + deg zero ----------------
__global__ void k_prep(const void* x,
                       const void* Wl1, const void* Wr1,
                       const void* Wl2, const void* Wr2, const void* Wl3, const void* Wr3,
                       const void* att1, const void* b1, const void* att2, const void* b2,
                       const void* att3, const void* b3,
                       u16* xb, u16* w1t, u16* w23t, float* params, int* deg) {
  const int b = blockIdx.x;
  const int t = threadIdx.x;
  const int isbf = is_bf16_w(x);
  if (!isbf) {
    int c = b * 256 + t;  // grid 12500 covers 3.2M chunks of 8
    const float* xf = (const float*)x + (size_t)c * 8;
    u32x4 o;
    #pragma unroll
    for (int i = 0; i < 4; ++i) {
      u32 lo = f2b(xf[2 * i]);
      u32 hi = f2b(xf[2 * i + 1]);
      o[i] = lo | (hi << 16);
    }
    *(u32x4*)(xb + (size_t)c * 8) = o;
  }
  if (b < 2048) {                       // w1t pack: [c][k], c<1024 (Wl1|Wr1)
    int tt = b * 256 + t;
    int k = tt >> 10, c = tt & 1023;
    const void* W = (c < 512) ? Wl1 : Wr1;
    int cc = c & 511;
    u16 v = isbf ? ((const u16*)W)[k * 512 + cc] : f2b(((const float*)W)[k * 512 + cc]);
    w1t[c * 512 + k] = v;
  } else if (b < 2240) {                // w23t pack: [c][k], c<96
    int tt = (b - 2048) * 256 + t;
    int k = tt / 96, c = tt % 96;
    const void* W = nullptr; int idx = 0;
    if (c < 40)      { W = Wl2; idx = k * 40 + c; }
    else if (c < 42) { W = Wl3; idx = k * 2 + (c - 40); }
    else if (c < 82) { W = Wr2; idx = k * 40 + (c - 42); }
    else if (c < 84) { W = Wr3; idx = k * 2 + (c - 82); }
    u16 v = 0;
    if (W) v = isbf ? ((const u16*)W)[idx] : f2b(((const float*)W)[idx]);
    w23t[c * 512 + k] = v;
  } else if (b < 2245) {                // params
    int tt = (b - 2240) * 256 + t;
    if (tt < 1108) {
      const void* src; int idx;
      if (tt < 512)       { src = att1; idx = tt; }
      else if (tt < 1024) { src = b1;   idx = tt - 512; }
      else if (tt < 1064) { src = att2; idx = tt - 1024; }
      else if (tt < 1104) { src = b2;   idx = tt - 1064; }
      else if (tt < 1106) { src = att3; idx = tt - 1104; }
      else                { src = b3;   idx = tt - 1106; }
      params[tt] = isbf ? b2f(((const u16*)src)[idx]) : ((const float*)src)[idx];
    }
  } else if (b < 2441) {                // zero deg
    int i = (b - 2245) * 256 + t;
    if (i < NN) deg[i] = 0;
  }
}

// ---------------- CSR build ----------------
__global__ void k_hist(const int* ei, int* deg) {
  int i64 = is_i64_w(ei);
  int e = blockIdx.x * 256 + threadIdx.x;
  if (e >= NE) return;
  int d = i64 ? ei[2 * (NE + e)] : ei[NE + e];
  atomicAdd(&deg[d], 1);
}

// single-block exclusive scan of deg+1 over 50000 entries
__global__ __launch_bounds__(1024) void k_scan(const int* __restrict__ deg, int* __restrict__ row_ptr,
                                               int* __restrict__ cursor) {
  __shared__ int wsum[16];
  int t = threadIdx.x;
  int lane = t & 63, wid = t >> 6;
  int base = t * 49;  // 1024*49 = 50176 >= NN
  int s = 0;
  for (int q = 0; q < 49; ++q) {
    int i = base + q;
    s += (i < NN) ? deg[i] + 1 : 0;
  }
  int incl = s;
  #pragma unroll
  for (int o = 1; o < 64; o <<= 1) {
    int u = __shfl_up(incl, o, 64);
    if (lane >= o) incl += u;
  }
  if (lane == 63) wsum[wid] = incl;
  __syncthreads();
  if (wid == 0) {
    int v = (lane < 16) ? wsum[lane] : 0;
    int iv = v;
    #pragma unroll
    for (int o = 1; o < 16; o <<= 1) {
      int u = __shfl_up(iv, o, 64);
      if (lane >= o) iv += u;
    }
    if (lane < 16) wsum[lane] = iv - v;  // exclusive wave prefix
  }
  __syncthreads();
  int run = wsum[wid] + incl - s;  // exclusive prefix for this thread
  for (int q = 0; q < 49; ++q) {
    int i = base + q;
    if (i < NN) {
      row_ptr[i] = run;
      cursor[i] = run;
      run += deg[i] + 1;
    }
  }
  if (t == 1023) row_ptr[NN] = run;
}

__global__ void k_scatter(const int* ei, int* cursor, int* csr_src) {
  int i64 = is_i64_w(ei);
  int t = blockIdx.x * 256 + threadIdx.x;
  if (t >= NT) return;
  int s, d;
  if (t < NE) {
    s = i64 ? ei[2 * t] : ei[t];
    d = i64 ? ei[2 * (NE + t)] : ei[NE + t];
  } else {
    s = d = t - NE;
  }
  int pos = atomicAdd(&cursor[d], 1);
  csr_src[pos] = s;
}

// ---------------- GEMM1: xl1/xr1[50000,512] = A @ w1t^T ----------------
// B-fragments loaded DIRECT from global (L2-hot: 1MB weight reused 49x per XCD)
// -> LDS carries only A (halved LDS traffic). Dual-chunk BK=64 halves barriers.
// XCD-aware mapping: XCD x owns m-tiles x*49.., all 8 n-tiles back-to-back.
__global__ __launch_bounds__(256) void k_gemm1(const void* __restrict__ xraw, const u16* __restrict__ xb,
                                               const u16* __restrict__ Bt,
                                               u16* __restrict__ XL, u16* __restrict__ XR) {
  __shared__ __align__(16) u16 As0[128 * 32];
  __shared__ __align__(16) u16 As1[128 * 32];
  const int isbf = is_bf16_w(xraw);   // before any return (ballot needs full wave)
  const int id  = blockIdx.x;
  const int xcd = id & 7;
  const int lb  = id >> 3;
  const int mt  = xcd * 49 + (lb >> 3);
  const int nt  = lb & 7;
  if (mt >= 391) return;
  const int m0 = mt * 128;
  const int n0 = nt * 128;
  const u16* __restrict__ A = isbf ? (const u16*)xraw : xb;
  const int t = threadIdx.x;
  const int wave = t >> 6;
  const int lane = t & 63;
  const int wm = (wave >> 1) * 64;
  const int wn = (wave & 1) * 64;
  const int fr = lane & 15;
  const int fk = lane >> 4;
  const int rsub = lane >> 2;                        // staging row within 16-row group
  const int achk = ((lane & 3) + (rsub >> 1)) & 3;   // swizzled source chunk
  const int sA = ((fk - (fr >> 1)) & 3) * 8;         // fragment slot (shorts)
  const u16* Brow = Bt + (size_t)(n0 + wn + fr) * 512 + fk * 8;
  f32x4 acc[4][4] = {};
  bf16x8 bb0[4], bb1[4];
  #pragma unroll
  for (int j = 0; j < 4; ++j) {
    bb0[j] = *(const bf16x8*)(Brow + (size_t)(j * 16) * 512);
    bb1[j] = *(const bf16x8*)(Brow + (size_t)(j * 16) * 512 + 32);
  }
  for (int k0 = 0; k0 < 512; k0 += 64) {
    #pragma unroll
    for (int c = 0; c < 2; ++c) {
      int rbase = wave * 16 + c * 64;
      int gm = m0 + rbase + rsub;
      if (gm > NN - 1) gm = NN - 1;   // clamp: never read past input x
      ld_lds16(&A[(size_t)gm * 512 + k0 + achk * 8], &As0[rbase * 32]);
      ld_lds16(&A[(size_t)gm * 512 + (k0 + 32) + achk * 8], &As1[rbase * 32]);
    }
    __syncthreads();
    bf16x8 af0[4], af1[4];
    #pragma unroll
    for (int i = 0; i < 4; ++i) af0[i] = *(const bf16x8*)&As0[(wm + i * 16 + fr) * 32 + sA];
    #pragma unroll
    for (int i = 0; i < 4; ++i) af1[i] = *(const bf16x8*)&As1[(wm + i * 16 + fr) * 32 + sA];
    #pragma unroll
    for (int i = 0; i < 4; ++i)
      #pragma unroll
      for (int j = 0; j < 4; ++j)
        acc[i][j] = __builtin_amdgcn_mfma_f32_16x16x32_bf16(af0[i], bb0[j], acc[i][j], 0, 0, 0);
    #pragma unroll
    for (int i = 0; i < 4; ++i)
      #pragma unroll
      for (int j = 0; j < 4; ++j)
        acc[i][j] = __builtin_amdgcn_mfma_f32_16x16x32_bf16(af1[i], bb1[j], acc[i][j], 0, 0, 0);
    __syncthreads();
    if (k0 + 64 < 512) {
      #pragma unroll
      for (int j = 0; j < 4; ++j) {
        bb0[j] = *(const bf16x8*)(Brow + (size_t)(j * 16) * 512 + (k0 + 64));
        bb1[j] = *(const bf16x8*)(Brow + (size_t)(j * 16) * 512 + (k0 + 96));
      }
    }
  }
  #pragma unroll
  for (int i = 0; i < 4; ++i) {
    #pragma unroll
    for (int r = 0; r < 4; ++r) {
      int gm = m0 + wm + i * 16 + fk * 4 + r;  // C/D: row=(lane>>4)*4+reg, col=lane&15
      if (gm < NN) {
        #pragma unroll
        for (int j = 0; j < 4; ++j) {
          int gn = n0 + wn + j * 16 + fr;
          u16 v = f2b(acc[i][j][r]);
          if (gn < 512) XL[(size_t)gm * 512 + gn] = v;
          else          XR[(size_t)gm * 512 + gn - 512] = v;
        }
      }
    }
  }
}

// ---------------- GEMM2: xlr23[50000,84] (bf16) = hb @ w23t^T, 128-row tiles ----------------
__global__ __launch_bounds__(256) void k_gemm2(const u16* __restrict__ A, const u16* __restrict__ Bt,
                                               u16* __restrict__ C) {
  __shared__ __align__(16) short As[128][40];
  __shared__ __align__(16) short Bs[96][40];
  const int m0 = blockIdx.x * 128;
  const int t = threadIdx.x;
  const int wave = t >> 6;
  const int lane = t & 63;
  const int fr = lane & 15;
  const int fk = lane >> 4;
  const int wm = wave * 32;
  f32x4 acc[2][6] = {};
  for (int k0 = 0; k0 < 512; k0 += 32) {
    #pragma unroll
    for (int h = 0; h < 2; ++h) {
      int c = t + h * 256;
      int row = c >> 2, kc = (c & 3) * 8;
      int gm = m0 + row;
      u32x4 va = {0, 0, 0, 0};
      if (gm < NN) va = *(const u32x4*)&A[(size_t)gm * 512 + k0 + kc];
      *(u32x4*)&As[row][kc] = va;
    }
    for (int c = t; c < 384; c += 256) {
      int row = c >> 2, kc = (c & 3) * 8;
      *(u32x4*)&Bs[row][kc] = *(const u32x4*)&Bt[row * 512 + k0 + kc];
    }
    __syncthreads();
    bf16x8 af[2], bb[6];
    #pragma unroll
    for (int i = 0; i < 2; ++i) af[i] = *(const bf16x8*)&As[wm + i * 16 + fr][fk * 8];
    #pragma unroll
    for (int j = 0; j < 6; ++j) bb[j] = *(const bf16x8*)&Bs[j * 16 + fr][fk * 8];
    #pragma unroll
    for (int i = 0; i < 2; ++i)
      #pragma unroll
      for (int j = 0; j < 6; ++j)
        acc[i][j] = __builtin_amdgcn_mfma_f32_16x16x32_bf16(af[i], bb[j], acc[i][j], 0, 0, 0);
    __syncthreads();
  }
  #pragma unroll
  for (int i = 0; i < 2; ++i) {
    #pragma unroll
    for (int j = 0; j < 6; ++j) {
      int gn = j * 16 + fr;
      if (gn < 84) {
        #pragma unroll
        for (int r = 0; r < 4; ++r) {
          int gm = m0 + wm + i * 16 + fk * 4 + r;
          if (gm < NN) C[(size_t)gm * 84 + gn] = f2b(acc[i][j][r]);
        }
      }
    }
  }
}

// ---------------- Layer 1 fused: one wave per node, 4 edges in flight ----------------
__global__ __launch_bounds__(256) void k_layer1f(const u16* __restrict__ xl1, const u16* __restrict__ xr1,
                                                 const int* __restrict__ row_ptr, const int* __restrict__ csr_src,
                                                 const float* __restrict__ params, u16* __restrict__ hb) {
  int wid = blockIdx.x * 4 + (threadIdx.x >> 6);
  int lane = threadIdx.x & 63;
  int nw = gridDim.x * 4;
  float att[8];
  #pragma unroll
  for (int k = 0; k < 8; ++k) att[k] = params[lane * 8 + k];
  for (int i = wid; i < NN; i += nw) {
    int e0 = row_ptr[i], e1 = row_ptr[i + 1];
    u32x4 xrv = *(const u32x4*)&xr1[(size_t)i * 512 + lane * 8];
    float xr[8];
    #pragma unroll
    for (int q = 0; q < 4; ++q) { xr[2 * q] = blo(xrv[q]); xr[2 * q + 1] = bhi(xrv[q]); }
    float s = 0.f;
    float acc[8] = {0.f, 0.f, 0.f, 0.f, 0.f, 0.f, 0.f, 0.f};
    for (int p = e0; p < e1; p += 4) {
      int p1 = p + 1 < e1 ? p + 1 : e1 - 1;
      int p2 = p + 2 < e1 ? p + 2 : e1 - 1;
      int p3 = p + 3 < e1 ? p + 3 : e1 - 1;
      int j0 = csr_src[p], j1 = csr_src[p1], j2 = csr_src[p2], j3 = csr_src[p3];
      u32x4 v0 = *(const u32x4*)&xl1[(size_t)j0 * 512 + lane * 8];
      u32x4 v1 = *(const u32x4*)&xl1[(size_t)j1 * 512 + lane * 8];
      u32x4 v2 = *(const u32x4*)&xl1[(size_t)j2 * 512 + lane * 8];
      u32x4 v3 = *(const u32x4*)&xl1[(size_t)j3 * 512 + lane * 8];
      float m1 = (p + 1 < e1) ? 1.f : 0.f;
      float m2 = (p + 2 < e1) ? 1.f : 0.f;
      float m3 = (p + 3 < e1) ? 1.f : 0.f;
      float c0 = 0.f, c1 = 0.f, c2 = 0.f, c3 = 0.f;
      float xlv0[8], xlv1[8], xlv2[8], xlv3[8];
      #pragma unroll
      for (int q = 0; q < 4; ++q) {
        xlv0[2 * q] = blo(v0[q]); xlv0[2 * q + 1] = bhi(v0[q]);
        xlv1[2 * q] = blo(v1[q]); xlv1[2 * q + 1] = bhi(v1[q]);
        xlv2[2 * q] = blo(v2[q]); xlv2[2 * q + 1] = bhi(v2[q]);
        xlv3[2 * q] = blo(v3[q]); xlv3[2 * q + 1] = bhi(v3[q]);
      }
      #pragma unroll
      for (int k = 0; k < 8; ++k) {
        float t0 = xlv0[k] + xr[k];
        float t1 = xlv1[k] + xr[k];
        float t2 = xlv2[k] + xr[k];
        float t3 = xlv3[k] + xr[k];
        c0 = fmaf(att[k], fmaxf(t0, 0.2f * t0), c0);
        c1 = fmaf(att[k], fmaxf(t1, 0.2f * t1), c1);
        c2 = fmaf(att[k], fmaxf(t2, 0.2f * t2), c2);
        c3 = fmaf(att[k], fmaxf(t3, 0.2f * t3), c3);
      }
      c0 += __shfl_xor(c0, 1, 64); c1 += __shfl_xor(c1, 1, 64);
      c2 += __shfl_xor(c2, 1, 64); c3 += __shfl_xor(c3, 1, 64);
      c0 += __shfl_xor(c0, 2, 64); c1 += __shfl_xor(c1, 2, 64);
      c2 += __shfl_xor(c2, 2, 64); c3 += __shfl_xor(c3, 2, 64);
      c0 += __shfl_xor(c0, 4, 64); c1 += __shfl_xor(c1, 4, 64);
      c2 += __shfl_xor(c2, 4, 64); c3 += __shfl_xor(c3, 4, 64);
      float pv0 = __expf(fminf(fmaxf(c0, -30.f), 30.f));
      float pv1 = __expf(fminf(fmaxf(c1, -30.f), 30.f)) * m1;
      float pv2 = __expf(fminf(fmaxf(c2, -30.f), 30.f)) * m2;
      float pv3 = __expf(fminf(fmaxf(c3, -30.f), 30.f)) * m3;
      s += (pv0 + pv1) + (pv2 + pv3);
      #pragma unroll
      for (int k = 0; k < 8; ++k) {
        float a = fmaf(pv0, xlv0[k], pv1 * xlv1[k]);
        float b = fmaf(pv2, xlv2[k], pv3 * xlv3[k]);
        acc[k] += a + b;
      }
    }
    float r = 1.f / s;
    u32x4 o;
    #pragma unroll
    for (int q = 0; q < 4; ++q) {
      u32 lo = f2b(fmaxf(fmaf(acc[2 * q],     r, params[512 + lane * 8 + 2 * q]),     0.f));
      u32 hi = f2b(fmaxf(fmaf(acc[2 * q + 1], r, params[512 + lane * 8 + 2 * q + 1]), 0.f));
      o[q] = lo | (hi << 16);
    }
    *(u32x4*)&hb[(size_t)i * 512 + lane * 8] = o;
  }
}

// ---------------- Layers 2+3 fused: one wave per node, 2 edges in flight (bf16 input) ----------------
__global__ __launch_bounds__(256) void k_layer23f(const void* __restrict__ xref, const u16* __restrict__ xlr23,
                                                  const int* __restrict__ row_ptr, const int* __restrict__ csr_src,
                                                  const float* __restrict__ params, void* __restrict__ out) {
  int isbf = is_bf16_w(xref);
  int wid = blockIdx.x * 4 + (threadIdx.x >> 6);
  int lane = threadIdx.x & 63;
  int nw = gridDim.x * 4;
  int c = lane;
  bool act = c < 42;
  float att = 0.f;
  if (c < 40)      att = params[1024 + c];
  else if (c < 42) att = params[1104 + (c - 40)];
  for (int i = wid; i < NN; i += nw) {
    int e0 = row_ptr[i], e1 = row_ptr[i + 1];
    float xr = act ? b2f(xlr23[(size_t)i * 84 + 42 + c]) : 0.f;
    float s2 = 0.f, s3 = 0.f, acc = 0.f;
    for (int p = e0; p < e1; p += 2) {
      int p1 = p + 1 < e1 ? p + 1 : e1 - 1;
      float m1 = (p + 1 < e1) ? 1.f : 0.f;
      int j0 = csr_src[p], j1 = csr_src[p1];
      float xl0 = act ? b2f(xlr23[(size_t)j0 * 84 + c]) : 0.f;
      float xl1 = act ? b2f(xlr23[(size_t)j1 * 84 + c]) : 0.f;
      float t0 = xl0 + xr, t1 = xl1 + xr;
      float v0 = att * fmaxf(t0, 0.2f * t0);
      float v1 = att * fmaxf(t1, 0.2f * t1);
      float w0 = (c < 40) ? v0 : 0.f;
      float w1 = (c < 40) ? v1 : 0.f;
      #pragma unroll
      for (int o = 32; o >= 1; o >>= 1) { w0 += __shfl_xor(w0, o, 64); w1 += __shfl_xor(w1, o, 64); }
      float u0 = v0 + __shfl_xor(v0, 1, 64);
      float u1 = v1 + __shfl_xor(v1, 1, 64);
      float l3_0 = __shfl(u0, 40, 64);
      float l3_1 = __shfl(u1, 40, 64);
      float p2_0 = __expf(fminf(fmaxf(w0, -30.f), 30.f));
      float p2_1 = __expf(fminf(fmaxf(w1, -30.f), 30.f)) * m1;
      float p3_0 = __expf(fminf(fmaxf(l3_0, -30.f), 30.f));
      float p3_1 = __expf(fminf(fmaxf(l3_1, -30.f), 30.f)) * m1;
      s2 += p2_0 + p2_1;
      s3 += p3_0 + p3_1;
      float a0 = (c < 40) ? p2_0 : p3_0;
      float a1 = (c < 40) ? p2_1 : p3_1;
      acc += fmaf(a0, xl0, a1 * xl1);
    }
    if (c < 40) {
      float v = acc / s2 + params[1064 + c];
      size_t o = (size_t)i * 40 + c;
      if (isbf) ((u16*)out)[o] = f2b(v); else ((float*)out)[o] = v;
    } else if (c < 42) {
      float v = acc / s3 + params[1106 + (c - 40)];
      size_t o = 2000000 + (size_t)i * 2 + (c - 40);
      if (isbf) ((u16*)out)[o] = f2b(v); else ((float*)out)[o] = v;
    }
  }
}

extern "C" void kernel_launch(void* const* d_in, const int* in_sizes, int n_in,
                              void* d_out, int out_size, void* d_ws, size_t ws_size,
                              hipStream_t stream) {
  const void* x    = d_in[0];
  const int*  ei   = (const int*)d_in[1];
  const void* Wl1  = d_in[2];
  const void* Wr1  = d_in[3];
  const void* att1 = d_in[4];
  const void* b1   = d_in[5];
  const void* Wl2  = d_in[6];
  const void* Wr2  = d_in[7];
  const void* att2 = d_in[8];
  const void* b2   = d_in[9];
  const void* Wl3  = d_in[10];
  const void* Wr3  = d_in[11];
  const void* att3 = d_in[12];
  const void* b3   = d_in[13];
  (void)in_sizes; (void)n_in; (void)out_size;

  char* ws = (char*)d_ws;
  size_t off = 0;
  auto alloc = [&](size_t bytes) -> void* {
    void* p = ws + off;
    off = (off + bytes + 255) & ~(size_t)255;
    return p;
  };
  u16*   xb      = (u16*)  alloc((size_t)NN * 512 * 2);    // 51.2 MB (f32 fallback path)
  u16*   w1t     = (u16*)  alloc((size_t)1024 * 512 * 2);  // 1 MB
  u16*   xl1     = (u16*)  alloc((size_t)NN * 512 * 2);    // 51.2 MB
  u16*   xr1     = (u16*)  alloc((size_t)NN * 512 * 2);    // 51.2 MB
  u16*   hb      = (u16*)  alloc((size_t)NN * 512 * 2);    // 51.2 MB
  u16*   w23t    = (u16*)  alloc((size_t)96 * 512 * 2);
  u16*   xlr23   = (u16*)  alloc((size_t)NN * 84 * 2);     // 8.4 MB (bf16)
  float* params  = (float*)alloc(1108 * 4);
  int*   row_ptr = (int*)  alloc((NN + 1) * 4);
  int*   deg     = (int*)  alloc(NN * 4);
  int*   cursor  = (int*)  alloc(NN * 4);
  int*   csr_src = (int*)  alloc((NT + 16) * 4);
  if (ws_size < off) return;  // ~215 MB needed

  hipLaunchKernelGGL(k_prep, dim3(12500), dim3(256), 0, stream,
                     x, Wl1, Wr1, Wl2, Wr2, Wl3, Wr3, att1, b1, att2, b2, att3, b3,
                     xb, w1t, w23t, params, deg);
  hipLaunchKernelGGL(k_hist, dim3((NE + 255) / 256), dim3(256), 0, stream, ei, deg);
  hipLaunchKernelGGL(k_scan, dim3(1), dim3(1024), 0, stream, deg, row_ptr, cursor);
  hipLaunchKernelGGL(k_scatter, dim3((NT + 255) / 256), dim3(256), 0, stream, ei, cursor, csr_src);
  hipLaunchKernelGGL(k_gemm1, dim3(3136), dim3(256), 0, stream, x, xb, w1t, xl1, xr1);
  hipLaunchKernelGGL(k_layer1f, dim3(4096), dim3(256), 0, stream, xl1, xr1, row_ptr, csr_src, params, hb);
  hipLaunchKernelGGL(k_gemm2, dim3(391), dim3(256), 0, stream, hb, w23t, xlr23);
  hipLaunchKernelGGL(k_layer23f, dim3(4096), dim3(256), 0, stream, x, xlr23, row_ptr, csr_src, params, d_out);
}

// Round 8
// 472.078 us; speedup vs baseline: 1.3277x; 1.3277x over previous
//
#include <hip/hip_runtime.h>
#include <math.h>

typedef unsigned short u16;
typedef unsigned int   u32;
typedef __attribute__((ext_vector_type(8))) short bf16x8;
typedef __attribute__((ext_vector_type(4))) float f32x4;
typedef __attribute__((ext_vector_type(4))) u32   u32x4;

__device__ __forceinline__ float b2f(u16 u) {
  union { u32 i; float f; } v; v.i = ((u32)u) << 16; return v.f;
}
__device__ __forceinline__ u16 f2b(float f) {
  union { u32 i; float f; } v; v.f = f;
  u32 r = v.i + 0x7FFFu + ((v.i >> 16) & 1u);
  return (u16)(r >> 16);
}
__device__ __forceinline__ float blo(u32 w) {
  union { u32 i; float f; } v; v.i = w << 16; return v.f;
}
__device__ __forceinline__ float bhi(u32 w) {
  union { u32 i; float f; } v; v.i = w & 0xFFFF0000u; return v.f;
}
// async global->LDS, 16B per lane; dest is wave-uniform base + lane*16
__device__ __forceinline__ void ld_lds16(const u16* g, u16* l) {
  __builtin_amdgcn_global_load_lds((const __attribute__((address_space(1))) void*)g,
                                   (__attribute__((address_space(3))) void*)l, 16, 0, 0);
}

#define NN 50000
#define NE 400000
#define NT 450000   // NE + NN self loops
#define NBLK_SCAN 196  // ceil(50000/256)

// ---------------- dtype detection ----------------
__global__ void k_detect(const void* x, const void* ei, int* flags) {
  __shared__ int cnt[2];
  int t = threadIdx.x; // 128 threads
  if (t < 2) cnt[t] = 0;
  __syncthreads();
  u16 u = ((const u16*)x)[t];
  int e = (u >> 7) & 0xFF;
  if (u == 0 || (e >= 90 && e <= 134)) atomicAdd(&cnt[0], 1);
  if (t < 16) {
    if (((const int*)ei)[2 * t + 1] == 0) atomicAdd(&cnt[1], 1);
  }
  __syncthreads();
  if (t == 0) {
    flags[0] = (cnt[0] >= 110) ? 1 : 0;
    flags[1] = (cnt[1] >= 15) ? 1 : 0;
  }
}

__device__ __forceinline__ int eidx(const int* ei, int pos, int i64) {
  return i64 ? ei[2 * pos] : ei[pos];
}

// ---------------- conversions / packing ----------------
__global__ void k_convert_x(const void* x, const int* flags, u16* xb) {
  if (flags[0]) return;
  int c = blockIdx.x * 256 + threadIdx.x;  // chunk of 8 elems
  const float* xf = (const float*)x + (size_t)c * 8;
  u32x4 o;
  #pragma unroll
  for (int i = 0; i < 4; ++i) {
    u32 lo = f2b(xf[2 * i]);
    u32 hi = f2b(xf[2 * i + 1]);
    o[i] = lo | (hi << 16);
  }
  *(u32x4*)(xb + (size_t)c * 8) = o;
}

__global__ void k_pack_w1t(const void* Wl1, const void* Wr1, const int* flags, u16* w1t) {
  int t = blockIdx.x * 256 + threadIdx.x;
  int k = t >> 10;
  int c = t & 1023;
  const void* W = (c < 512) ? Wl1 : Wr1;
  int cc = c & 511;
  u16 v;
  if (flags[0]) v = ((const u16*)W)[k * 512 + cc];
  else          v = f2b(((const float*)W)[k * 512 + cc]);
  w1t[c * 512 + k] = v;
}

__global__ void k_pack_w23t(const void* Wl2, const void* Wr2, const void* Wl3, const void* Wr3,
                            const int* flags, u16* w23t) {
  int t = blockIdx.x * 256 + threadIdx.x;
  int k = t / 96;
  int c = t % 96;
  const void* W = nullptr; int idx = 0;
  if (c < 40)      { W = Wl2; idx = k * 40 + c; }
  else if (c < 42) { W = Wl3; idx = k * 2 + (c - 40); }
  else if (c < 82) { W = Wr2; idx = k * 40 + (c - 42); }
  else if (c < 84) { W = Wr3; idx = k * 2 + (c - 82); }
  u16 v = 0;
  if (W) {
    if (flags[0]) v = ((const u16*)W)[idx];
    else          v = f2b(((const float*)W)[idx]);
  }
  w23t[c * 512 + k] = v;
}

__global__ void k_pack_params(const void* att1, const void* b1, const void* att2, const void* b2,
                              const void* att3, const void* b3, const int* flags, float* params) {
  int t = blockIdx.x * 256 + threadIdx.x;
  if (t >= 1108) return;
  const void* src; int idx;
  if (t < 512)       { src = att1; idx = t; }
  else if (t < 1024) { src = b1;   idx = t - 512; }
  else if (t < 1064) { src = att2; idx = t - 1024; }
  else if (t < 1104) { src = b2;   idx = t - 1064; }
  else if (t < 1106) { src = att3; idx = t - 1104; }
  else               { src = b3;   idx = t - 1106; }
  params[t] = flags[0] ? b2f(((const u16*)src)[idx]) : ((const float*)src)[idx];
}

// ---------------- CSR build ----------------
__global__ void k_hist(const int* ei, const int* flags, int* deg) {
  int e = blockIdx.x * 256 + threadIdx.x;
  if (e >= NE) return;
  int d = eidx(ei, NE + e, flags[1]);
  atomicAdd(&deg[d], 1);
}

__global__ void k_scanA(const int* deg, int* row_ptr, int* bsum) {
  __shared__ int sh[256];
  int b = blockIdx.x, t = threadIdx.x;
  int i = b * 256 + t;
  int val = (i < NN) ? deg[i] + 1 : 0;
  sh[t] = val;
  __syncthreads();
  #pragma unroll
  for (int off = 1; off < 256; off <<= 1) {
    int v = (t >= off) ? sh[t - off] : 0;
    __syncthreads();
    sh[t] += v;
    __syncthreads();
  }
  if (i < NN) row_ptr[i] = sh[t] - val;
  if (t == 255) bsum[b] = sh[255];
}

__global__ void k_scanB(int* bsum, int* row_ptr) {
  __shared__ int sh[256];
  int t = threadIdx.x;
  int val = (t < NBLK_SCAN) ? bsum[t] : 0;
  sh[t] = val;
  __syncthreads();
  #pragma unroll
  for (int off = 1; off < 256; off <<= 1) {
    int v = (t >= off) ? sh[t - off] : 0;
    __syncthreads();
    sh[t] += v;
    __syncthreads();
  }
  if (t < NBLK_SCAN) bsum[t] = sh[t] - val;
  if (t == 255) row_ptr[NN] = sh[255];
}

__global__ void k_scanC(const int* bsum, int* row_ptr, int* cursor) {
  int i = blockIdx.x * 256 + threadIdx.x;
  if (i < NN) {
    int v = row_ptr[i] + bsum[blockIdx.x];
    row_ptr[i] = v;
    cursor[i] = v;
  }
}

__global__ void k_scatter(const int* ei, const int* flags, int* cursor, int* csr_src) {
  int t = blockIdx.x * 256 + threadIdx.x;
  if (t >= NT) return;
  int i64 = flags[1];
  int s, d;
  if (t < NE) { s = eidx(ei, t, i64); d = eidx(ei, NE + t, i64); }
  else        { s = d = t - NE; }
  int pos = atomicAdd(&cursor[d], 1);
  csr_src[pos] = s;
}

// ---------------- GEMM1: xl1/xr1[50000,512] = A @ w1t^T ----------------
// BK=64, A+B staged in LDS via global_load_lds, XOR chunk swizzle (source-side,
// keeps LDS dest lane-contiguous) -> fragment ds_read_b128 2-way banks (free).
// XCD-aware mapping: XCD x owns m-tiles x*49.., all 8 n-tiles back-to-back.
__global__ __launch_bounds__(256) void k_gemm1(const void* __restrict__ xraw, const u16* __restrict__ xb,
                                               const u16* __restrict__ Bt, const int* __restrict__ flags,
                                               u16* __restrict__ XL, u16* __restrict__ XR) {
  __shared__ __align__(16) u16 As[128 * 64];
  __shared__ __align__(16) u16 Bs[128 * 64];
  const int id  = blockIdx.x;
  const int xcd = id & 7;
  const int lb  = id >> 3;
  const int mt  = xcd * 49 + (lb >> 3);
  const int nt  = lb & 7;
  if (mt >= 391) return;
  const int m0 = mt * 128;
  const int n0 = nt * 128;
  const u16* __restrict__ A = flags[0] ? (const u16*)xraw : xb;
  const int t = threadIdx.x;
  const int wave = t >> 6;
  const int lane = t & 63;
  const int wm = (wave >> 1) * 64;
  const int wn = (wave & 1) * 64;
  const int fr = lane & 15;
  const int fk = lane >> 4;
  const int srow = lane >> 3;               // 0..7: row within 8-row staging group
  const int schk = (lane & 7) ^ srow;       // XOR-swizzled source chunk (16B units)
  f32x4 acc[4][4] = {};
  for (int k0 = 0; k0 < 512; k0 += 64) {
    #pragma unroll
    for (int q = 0; q < 4; ++q) {
      int rbase = wave * 32 + q * 8;        // wave stages rows [wave*32, wave*32+32)
      int gm = m0 + rbase + srow;
      if (gm > NN - 1) gm = NN - 1;         // clamp: never read past input x
      ld_lds16(&A[(size_t)gm * 512 + k0 + schk * 8], &As[rbase * 64]);
      ld_lds16(&Bt[(size_t)(n0 + rbase + srow) * 512 + k0 + schk * 8], &Bs[rbase * 64]);
    }
    __syncthreads();
    #pragma unroll
    for (int h = 0; h < 2; ++h) {
      int s = h * 4 + fk;                   // k-chunk select 0..7
      bf16x8 af[4], bb[4];
      #pragma unroll
      for (int i = 0; i < 4; ++i) {
        int row = wm + i * 16 + fr;
        af[i] = *(const bf16x8*)&As[row * 64 + ((s ^ (row & 7)) * 8)];
      }
      #pragma unroll
      for (int j = 0; j < 4; ++j) {
        int row = wn + j * 16 + fr;
        bb[j] = *(const bf16x8*)&Bs[row * 64 + ((s ^ (row & 7)) * 8)];
      }
      #pragma unroll
      for (int i = 0; i < 4; ++i)
        #pragma unroll
        for (int j = 0; j < 4; ++j)
          acc[i][j] = __builtin_amdgcn_mfma_f32_16x16x32_bf16(af[i], bb[j], acc[i][j], 0, 0, 0);
    }
    __syncthreads();
  }
  #pragma unroll
  for (int i = 0; i < 4; ++i) {
    #pragma unroll
    for (int r = 0; r < 4; ++r) {
      int gm = m0 + wm + i * 16 + fk * 4 + r;  // C/D: row=(lane>>4)*4+reg, col=lane&15
      if (gm < NN) {
        #pragma unroll
        for (int j = 0; j < 4; ++j) {
          int gn = n0 + wn + j * 16 + fr;
          u16 v = f2b(acc[i][j][r]);
          if (gn < 512) XL[(size_t)gm * 512 + gn] = v;
          else          XR[(size_t)gm * 512 + gn - 512] = v;
        }
      }
    }
  }
}

// ---------------- GEMM2: xlr23[50000,84] = hb @ w23t^T, 128-row tiles ----------------
__global__ __launch_bounds__(256) void k_gemm2(const u16* __restrict__ A, const u16* __restrict__ Bt,
                                               float* __restrict__ C) {
  __shared__ __align__(16) short As[128][40];
  __shared__ __align__(16) short Bs[96][40];
  const int m0 = blockIdx.x * 128;
  const int t = threadIdx.x;
  const int wave = t >> 6;
  const int lane = t & 63;
  const int fr = lane & 15;
  const int fk = lane >> 4;
  const int wm = wave * 32;
  f32x4 acc[2][6] = {};
  for (int k0 = 0; k0 < 512; k0 += 32) {
    #pragma unroll
    for (int h = 0; h < 2; ++h) {
      int c = t + h * 256;
      int row = c >> 2, kc = (c & 3) * 8;
      int gm = m0 + row;
      u32x4 va = {0, 0, 0, 0};
      if (gm < NN) va = *(const u32x4*)&A[(size_t)gm * 512 + k0 + kc];
      *(u32x4*)&As[row][kc] = va;
    }
    for (int c = t; c < 384; c += 256) {
      int row = c >> 2, kc = (c & 3) * 8;
      *(u32x4*)&Bs[row][kc] = *(const u32x4*)&Bt[row * 512 + k0 + kc];
    }
    __syncthreads();
    bf16x8 af[2], bb[6];
    #pragma unroll
    for (int i = 0; i < 2; ++i) af[i] = *(const bf16x8*)&As[wm + i * 16 + fr][fk * 8];
    #pragma unroll
    for (int j = 0; j < 6; ++j) bb[j] = *(const bf16x8*)&Bs[j * 16 + fr][fk * 8];
    #pragma unroll
    for (int i = 0; i < 2; ++i)
      #pragma unroll
      for (int j = 0; j < 6; ++j)
        acc[i][j] = __builtin_amdgcn_mfma_f32_16x16x32_bf16(af[i], bb[j], acc[i][j], 0, 0, 0);
    __syncthreads();
  }
  #pragma unroll
  for (int i = 0; i < 2; ++i) {
    #pragma unroll
    for (int j = 0; j < 6; ++j) {
      int gn = j * 16 + fr;
      if (gn < 84) {
        #pragma unroll
        for (int r = 0; r < 4; ++r) {
          int gm = m0 + wm + i * 16 + fk * 4 + r;
          if (gm < NN) C[(size_t)gm * 84 + gn] = acc[i][j][r];
        }
      }
    }
  }
}

// ---------------- Layer 1 fused: one wave per node, 4 edges in flight + index prefetch ----------------
__global__ __launch_bounds__(256) void k_layer1f(const u16* __restrict__ xl1, const u16* __restrict__ xr1,
                                                 const int* __restrict__ row_ptr, const int* __restrict__ csr_src,
                                                 const float* __restrict__ params, u16* __restrict__ hb) {
  int wid = blockIdx.x * 4 + (threadIdx.x >> 6);
  int lane = threadIdx.x & 63;
  int nw = gridDim.x * 4;
  float att[8];
  #pragma unroll
  for (int k = 0; k < 8; ++k) att[k] = params[lane * 8 + k];
  for (int i = wid; i < NN; i += nw) {
    int e0 = row_ptr[i], e1 = row_ptr[i + 1];
    u32x4 xrv = *(const u32x4*)&xr1[(size_t)i * 512 + lane * 8];
    float xr[8];
    #pragma unroll
    for (int q = 0; q < 4; ++q) { xr[2 * q] = blo(xrv[q]); xr[2 * q + 1] = bhi(xrv[q]); }
    float s = 0.f;
    float acc[8] = {0.f, 0.f, 0.f, 0.f, 0.f, 0.f, 0.f, 0.f};
    // index prefetch: indices for iteration p are loaded during iteration p-4
    int q0 = csr_src[e0];
    int q1 = csr_src[e0 + 1 < e1 ? e0 + 1 : e1 - 1];
    int q2 = csr_src[e0 + 2 < e1 ? e0 + 2 : e1 - 1];
    int q3 = csr_src[e0 + 3 < e1 ? e0 + 3 : e1 - 1];
    for (int p = e0; p < e1; p += 4) {
      int j0 = q0, j1 = q1, j2 = q2, j3 = q3;
      u32x4 v0 = *(const u32x4*)&xl1[(size_t)j0 * 512 + lane * 8];
      u32x4 v1 = *(const u32x4*)&xl1[(size_t)j1 * 512 + lane * 8];
      u32x4 v2 = *(const u32x4*)&xl1[(size_t)j2 * 512 + lane * 8];
      u32x4 v3 = *(const u32x4*)&xl1[(size_t)j3 * 512 + lane * 8];
      int np = p + 4;
      if (np < e1) {
        q0 = csr_src[np];
        q1 = csr_src[np + 1 < e1 ? np + 1 : e1 - 1];
        q2 = csr_src[np + 2 < e1 ? np + 2 : e1 - 1];
        q3 = csr_src[np + 3 < e1 ? np + 3 : e1 - 1];
      }
      float m1 = (p + 1 < e1) ? 1.f : 0.f;
      float m2 = (p + 2 < e1) ? 1.f : 0.f;
      float m3 = (p + 3 < e1) ? 1.f : 0.f;
      float c0 = 0.f, c1 = 0.f, c2 = 0.f, c3 = 0.f;
      float xlv0[8], xlv1[8], xlv2[8], xlv3[8];
      #pragma unroll
      for (int q = 0; q < 4; ++q) {
        xlv0[2 * q] = blo(v0[q]); xlv0[2 * q + 1] = bhi(v0[q]);
        xlv1[2 * q] = blo(v1[q]); xlv1[2 * q + 1] = bhi(v1[q]);
        xlv2[2 * q] = blo(v2[q]); xlv2[2 * q + 1] = bhi(v2[q]);
        xlv3[2 * q] = blo(v3[q]); xlv3[2 * q + 1] = bhi(v3[q]);
      }
      #pragma unroll
      for (int k = 0; k < 8; ++k) {
        float t0 = xlv0[k] + xr[k];
        float t1 = xlv1[k] + xr[k];
        float t2 = xlv2[k] + xr[k];
        float t3 = xlv3[k] + xr[k];
        c0 = fmaf(att[k], fmaxf(t0, 0.2f * t0), c0);
        c1 = fmaf(att[k], fmaxf(t1, 0.2f * t1), c1);
        c2 = fmaf(att[k], fmaxf(t2, 0.2f * t2), c2);
        c3 = fmaf(att[k], fmaxf(t3, 0.2f * t3), c3);
      }
      c0 += __shfl_xor(c0, 1, 64); c1 += __shfl_xor(c1, 1, 64);
      c2 += __shfl_xor(c2, 1, 64); c3 += __shfl_xor(c3, 1, 64);
      c0 += __shfl_xor(c0, 2, 64); c1 += __shfl_xor(c1, 2, 64);
      c2 += __shfl_xor(c2, 2, 64); c3 += __shfl_xor(c3, 2, 64);
      c0 += __shfl_xor(c0, 4, 64); c1 += __shfl_xor(c1, 4, 64);
      c2 += __shfl_xor(c2, 4, 64); c3 += __shfl_xor(c3, 4, 64);
      float pv0 = __expf(fminf(fmaxf(c0, -30.f), 30.f));
      float pv1 = __expf(fminf(fmaxf(c1, -30.f), 30.f)) * m1;
      float pv2 = __expf(fminf(fmaxf(c2, -30.f), 30.f)) * m2;
      float pv3 = __expf(fminf(fmaxf(c3, -30.f), 30.f)) * m3;
      s += (pv0 + pv1) + (pv2 + pv3);
      #pragma unroll
      for (int k = 0; k < 8; ++k) {
        float a = fmaf(pv0, xlv0[k], pv1 * xlv1[k]);
        float b = fmaf(pv2, xlv2[k], pv3 * xlv3[k]);
        acc[k] += a + b;
      }
    }
    float r = 1.f / s;
    u32x4 o;
    #pragma unroll
    for (int q = 0; q < 4; ++q) {
      u32 lo = f2b(fmaxf(fmaf(acc[2 * q],     r, params[512 + lane * 8 + 2 * q]),     0.f));
      u32 hi = f2b(fmaxf(fmaf(acc[2 * q + 1], r, params[512 + lane * 8 + 2 * q + 1]), 0.f));
      o[q] = lo | (hi << 16);
    }
    *(u32x4*)&hb[(size_t)i * 512 + lane * 8] = o;
  }
}

// ---------------- Layers 2+3 fused: one wave per node, 2 edges in flight ----------------
__global__ __launch_bounds__(256) void k_layer23f(const float* __restrict__ xlr23, const int* __restrict__ row_ptr,
                                                  const int* __restrict__ csr_src, const float* __restrict__ params,
                                                  const int* __restrict__ flags, void* __restrict__ out) {
  int wid = blockIdx.x * 4 + (threadIdx.x >> 6);
  int lane = threadIdx.x & 63;
  int nw = gridDim.x * 4;
  int c = lane;
  bool act = c < 42;
  float att = 0.f;
  if (c < 40)      att = params[1024 + c];
  else if (c < 42) att = params[1104 + (c - 40)];
  int isbf = flags[0];
  for (int i = wid; i < NN; i += nw) {
    int e0 = row_ptr[i], e1 = row_ptr[i + 1];
    float xr = act ? xlr23[(size_t)i * 84 + 42 + c] : 0.f;
    float s2 = 0.f, s3 = 0.f, acc = 0.f;
    for (int p = e0; p < e1; p += 2) {
      int p1 = p + 1 < e1 ? p + 1 : e1 - 1;
      float m1 = (p + 1 < e1) ? 1.f : 0.f;
      int j0 = csr_src[p], j1 = csr_src[p1];
      float xl0 = act ? xlr23[(size_t)j0 * 84 + c] : 0.f;
      float xl1 = act ? xlr23[(size_t)j1 * 84 + c] : 0.f;
      float t0 = xl0 + xr, t1 = xl1 + xr;
      float v0 = att * fmaxf(t0, 0.2f * t0);
      float v1 = att * fmaxf(t1, 0.2f * t1);
      float w0 = (c < 40) ? v0 : 0.f;
      float w1 = (c < 40) ? v1 : 0.f;
      #pragma unroll
      for (int o = 32; o >= 1; o >>= 1) { w0 += __shfl_xor(w0, o, 64); w1 += __shfl_xor(w1, o, 64); }
      float u0 = v0 + __shfl_xor(v0, 1, 64);
      float u1 = v1 + __shfl_xor(v1, 1, 64);
      float l3_0 = __shfl(u0, 40, 64);
      float l3_1 = __shfl(u1, 40, 64);
      float p2_0 = __expf(fminf(fmaxf(w0, -30.f), 30.f));
      float p2_1 = __expf(fminf(fmaxf(w1, -30.f), 30.f)) * m1;
      float p3_0 = __expf(fminf(fmaxf(l3_0, -30.f), 30.f));
      float p3_1 = __expf(fminf(fmaxf(l3_1, -30.f), 30.f)) * m1;
      s2 += p2_0 + p2_1;
      s3 += p3_0 + p3_1;
      float a0 = (c < 40) ? p2_0 : p3_0;
      float a1 = (c < 40) ? p2_1 : p3_1;
      acc += fmaf(a0, xl0, a1 * xl1);
    }
    if (c < 40) {
      float v = acc / s2 + params[1064 + c];
      size_t o = (size_t)i * 40 + c;
      if (isbf) ((u16*)out)[o] = f2b(v); else ((float*)out)[o] = v;
    } else if (c < 42) {
      float v = acc / s3 + params[1106 + (c - 40)];
      size_t o = 2000000 + (size_t)i * 2 + (c - 40);
      if (isbf) ((u16*)out)[o] = f2b(v); else ((float*)out)[o] = v;
    }
  }
}

extern "C" void kernel_launch(void* const* d_in, const int* in_sizes, int n_in,
                              void* d_out, int out_size, void* d_ws, size_t ws_size,
                              hipStream_t stream) {
  const void* x    = d_in[0];
  const int*  ei   = (const int*)d_in[1];
  const void* Wl1  = d_in[2];
  const void* Wr1  = d_in[3];
  const void* att1 = d_in[4];
  const void* b1   = d_in[5];
  const void* Wl2  = d_in[6];
  const void* Wr2  = d_in[7];
  const void* att2 = d_in[8];
  const void* b2   = d_in[9];
  const void* Wl3  = d_in[10];
  const void* Wr3  = d_in[11];
  const void* att3 = d_in[12];
  const void* b3   = d_in[13];
  (void)in_sizes; (void)n_in; (void)out_size;

  char* ws = (char*)d_ws;
  size_t off = 0;
  auto alloc = [&](size_t bytes) -> void* {
    void* p = ws + off;
    off = (off + bytes + 255) & ~(size_t)255;
    return p;
  };
  int*   flags   = (int*)  alloc(64);
  u16*   xb      = (u16*)  alloc((size_t)NN * 512 * 2);    // 51.2 MB (f32 fallback path)
  u16*   w1t     = (u16*)  alloc((size_t)1024 * 512 * 2);  // 1 MB
  u16*   xl1     = (u16*)  alloc((size_t)NN * 512 * 2);    // 51.2 MB
  u16*   xr1     = (u16*)  alloc((size_t)NN * 512 * 2);    // 51.2 MB
  u16*   hb      = (u16*)  alloc((size_t)NN * 512 * 2);    // 51.2 MB
  u16*   w23t    = (u16*)  alloc((size_t)96 * 512 * 2);
  float* xlr23   = (float*)alloc((size_t)NN * 84 * 4);     // 16.8 MB
  float* params  = (float*)alloc(1108 * 4);
  int*   row_ptr = (int*)  alloc((NN + 1) * 4);
  int*   deg     = (int*)  alloc(NN * 4);
  int*   cursor  = (int*)  alloc(NN * 4);
  int*   csr_src = (int*)  alloc((NT + 16) * 4);
  int*   bsum    = (int*)  alloc(256 * 4);
  if (ws_size < off) return;  // ~225 MB needed

  hipLaunchKernelGGL(k_detect, dim3(1), dim3(128), 0, stream, x, (const void*)ei, flags);
  hipLaunchKernelGGL(k_convert_x, dim3(12500), dim3(256), 0, stream, x, flags, xb);
  hipLaunchKernelGGL(k_pack_w1t, dim3(2048), dim3(256), 0, stream, Wl1, Wr1, flags, w1t);
  hipLaunchKernelGGL(k_pack_w23t, dim3(192), dim3(256), 0, stream, Wl2, Wr2, Wl3, Wr3, flags, w23t);
  hipLaunchKernelGGL(k_pack_params, dim3(5), dim3(256), 0, stream, att1, b1, att2, b2, att3, b3, flags, params);
  hipMemsetAsync(deg, 0, NN * 4, stream);
  hipLaunchKernelGGL(k_hist, dim3((NE + 255) / 256), dim3(256), 0, stream, ei, flags, deg);
  hipLaunchKernelGGL(k_scanA, dim3(NBLK_SCAN), dim3(256), 0, stream, deg, row_ptr, bsum);
  hipLaunchKernelGGL(k_scanB, dim3(1), dim3(256), 0, stream, bsum, row_ptr);
  hipLaunchKernelGGL(k_scanC, dim3(NBLK_SCAN), dim3(256), 0, stream, bsum, row_ptr, cursor);
  hipLaunchKernelGGL(k_scatter, dim3((NT + 255) / 256), dim3(256), 0, stream, ei, flags, cursor, csr_src);
  hipLaunchKernelGGL(k_gemm1, dim3(3136), dim3(256), 0, stream, x, xb, w1t, flags, xl1, xr1);
  hipLaunchKernelGGL(k_layer1f, dim3(4096), dim3(256), 0, stream, xl1, xr1, row_ptr, csr_src, params, hb);
  hipLaunchKernelGGL(k_gemm2, dim3(391), dim3(256), 0, stream, hb, w23t, xlr23);
  hipLaunchKernelGGL(k_layer23f, dim3(4096), dim3(256), 0, stream, xlr23, row_ptr, csr_src, params, flags, d_out);
}